// Round 10
// baseline (260.568 us; speedup 1.0000x reference)
//
#include <hip/hip_runtime.h>
#include <hip/hip_bf16.h>

typedef short bf16x8 __attribute__((ext_vector_type(8)));
typedef float f32x4 __attribute__((ext_vector_type(4)));
using bf16 = __hip_bfloat16;

#define MFMA16(a, b, c) __builtin_amdgcn_mfma_f32_16x16x32_bf16(a, b, c, 0, 0, 0)

typedef unsigned int u32;
typedef u32 __attribute__((address_space(1))) global_u32;
typedef u32 __attribute__((address_space(3))) lds_u32;

__device__ __forceinline__ void gload_lds16(const unsigned short* g, unsigned short* l) {
    // async 16B/lane global->LDS DMA; LDS dest = wave-uniform base + lane*16
    __builtin_amdgcn_global_load_lds((const global_u32*)g, (lds_u32*)l, 16, 0, 0);
}

__device__ __forceinline__ short f2b(float f) {
    __hip_bfloat16 h = __float2bfloat16(f);  // RNE
    return *reinterpret_cast<short*>(&h);
}

__device__ __forceinline__ float exp2_fast(float x) {
    float r;
    asm("v_exp_f32 %0, %1" : "=v"(r) : "v"(x));
    return r;
}

// Packed bf16 pair (RTZ single instruction). Safe here ONLY because the softmax
// denominator is computed from the SAME packed values (ratio cancellation):
// O = sum(Phat*v)/sum(Phat) -> the truncation bias cancels exactly in the ratio.
// (R6 failed with cvt_pk because lst came from pre-pack f32 -> bias uncancelled.)
__device__ __forceinline__ u32 cvt_pk_bf16(float lo, float hi) {
    u32 r;
    asm("v_cvt_pk_bf16_f32 %0, %1, %2" : "=v"(r) : "v"(lo), "v"(hi));
    return r;
}

// Q pre-scale: D^-0.5 * log2(e); attn then uses exp2 -> saves one v_mul per score
#define QSCALE 0.18033688011112042f

// ---------- fp32 -> bf16 convert, all three inputs in ONE launch ----------
__global__ __launch_bounds__(256) void cvt3_kernel(const float* __restrict__ x,
                                                   const float* __restrict__ wq,
                                                   const float* __restrict__ wo,
                                                   unsigned short* __restrict__ xb,
                                                   unsigned short* __restrict__ wqb,
                                                   unsigned short* __restrict__ wob) {
    const int id = blockIdx.x;
    const float* src;
    unsigned short* dst;
    size_t off;
    if (id < 4096) {
        src = x; dst = xb; off = (size_t)id * 2048;
    } else if (id < 5632) {
        src = wq; dst = wqb; off = (size_t)(id - 4096) * 2048;
    } else {
        src = wo; dst = wob; off = (size_t)(id - 5632) * 2048;
    }
    const size_t i = off + (size_t)threadIdx.x * 8;
    float4 v0 = *(const float4*)(src + i);
    float4 v1 = *(const float4*)(src + i + 4);
    bf16x8 o;
    o[0] = f2b(v0.x); o[1] = f2b(v0.y); o[2] = f2b(v0.z); o[3] = f2b(v0.w);
    o[4] = f2b(v1.x); o[5] = f2b(v1.y); o[6] = f2b(v1.z); o[7] = f2b(v1.w);
    *(bf16x8*)(dst + i) = o;
}

// ---------- m97-structure bf16 GEMM (kept for out-projection, MODE 1) ----------
template <int MODE>
__global__ __launch_bounds__(256) void gemm128_kernel(const unsigned short* __restrict__ A,
                                                      const unsigned short* __restrict__ W,
                                                      void* __restrict__ outp) {
    __shared__ unsigned short As[128][64];
    __shared__ unsigned short Ws[128][64];
    const int tid = threadIdx.x;
    const int lane = tid & 63;
    const int w = tid >> 6;
    const int wr = w >> 1, wc = w & 1;
    const int lm = lane & 15, quad = lane >> 4;
    const int m0 = blockIdx.y * 128, n0 = blockIdx.x * 128;

    const int srow8 = lane >> 3;
    const int skg = (lane & 7) ^ srow8;
    const unsigned short* Ag = A + (size_t)(m0 + w * 32 + srow8) * 1024 + skg * 8;
    const unsigned short* Wg = W + (size_t)(n0 + w * 32 + srow8) * 1024 + skg * 8;

    f32x4 acc[4][4] = {};

    for (int k0 = 0; k0 < 1024; k0 += 64) {
        __syncthreads();
#pragma unroll
        for (int j = 0; j < 4; j++) {
            gload_lds16(Ag + j * (8 * 1024), &As[w * 32 + j * 8][0]);
            gload_lds16(Wg + j * (8 * 1024), &Ws[w * 32 + j * 8][0]);
        }
        Ag += 64;
        Wg += 64;
        __syncthreads();
#pragma unroll
        for (int ks = 0; ks < 2; ks++) {
            const int swz = ((quad + ks * 4) ^ (lm & 7)) * 8;
            bf16x8 af[4], bf[4];
#pragma unroll
            for (int mt = 0; mt < 4; mt++)
                af[mt] = *(const bf16x8*)&As[wr * 64 + mt * 16 + lm][swz];
#pragma unroll
            for (int nt = 0; nt < 4; nt++)
                bf[nt] = *(const bf16x8*)&Ws[wc * 64 + nt * 16 + lm][swz];
#pragma unroll
            for (int mt = 0; mt < 4; mt++)
#pragma unroll
                for (int nt = 0; nt < 4; nt++)
                    acc[mt][nt] = MFMA16(af[mt], bf[nt], acc[mt][nt]);
        }
    }

#pragma unroll
    for (int mt = 0; mt < 4; mt++)
#pragma unroll
        for (int nt = 0; nt < 4; nt++) {
            f32x4 v = acc[mt][nt];
            const int gr0 = m0 + wr * 64 + mt * 16 + quad * 4;
            const int gc = n0 + wc * 64 + nt * 16 + lm;
            if (MODE == 2) {
                bf16* qkv = (bf16*)outp;
                const int which = gc >> 10;
                const int h = (gc >> 6) & 15;
                const int d = gc & 63;
                const int b = gr0 >> 11, n = gr0 & 2047;
                if (which == 2) {
                    short4 pk;
                    pk.x = f2b(v[0]); pk.y = f2b(v[1]); pk.z = f2b(v[2]); pk.w = f2b(v[3]);
                    *(short4*)&qkv[2ull * 8388608 +
                                   ((size_t)((b * 16 + h) * 64 + d)) * 2048 + n] = pk;
                } else {
#pragma unroll
                    for (int r = 0; r < 4; r++) {
                        float val = v[r];
                        if (which == 0) val *= QSCALE;
                        qkv[(size_t)which * 8388608 +
                            ((size_t)((b * 16 + h) * 2048 + n + r)) * 64 + d] =
                            __float2bfloat16(val);
                    }
                }
            } else {
                float* o = (float*)outp;
#pragma unroll
                for (int r = 0; r < 4; r++) o[(size_t)(gr0 + r) * 1024 + gc] = v[r];
            }
        }
}

// ---------- 256x128 8-phase bf16 GEMM for the QKV projection (R2, passed) ----------
__global__ __launch_bounds__(512, 2) void gemm256x128_qkv_kernel(
    const unsigned short* __restrict__ A,   // [8192,1024] bf16
    const unsigned short* __restrict__ W,   // [3072,1024] bf16
    unsigned short* __restrict__ qkvp) {
    __shared__ unsigned short As[2][256][64];
    __shared__ unsigned short Bs[2][128][64];
    const int tid = threadIdx.x;
    const int lane = tid & 63;
    const int w = tid >> 6;               // 0..7
    const int wr = w >> 1, wc = w & 1;    // 4M x 2N wave grid
    const int lm = lane & 15, quad = lane >> 4;

    const int id = blockIdx.x;
    const int xs = (id & 7) * 96 + (id >> 3);
    const int n0 = (xs % 24) * 128;
    const int m0 = (xs / 24) * 256;

    const int sr = lane >> 3;
    const int sg = (lane & 7) ^ sr;
    const unsigned short* Ab = A + (size_t)(m0 + w * 8 + sr) * 1024 + sg * 8;
    const unsigned short* Wb = W + (size_t)(n0 + w * 8 + sr) * 1024 + sg * 8;

    f32x4 acc[4][4] = {};
    bf16x8 af[2][2];
    bf16x8 bfA[2][2];
    bf16x8 bfB[2][2];

#define STAGE_A(buf, half, kk)                                                     \
    do {                                                                           \
        gload_lds16(Ab + (size_t)((half) * 128) * 1024 + (kk),                     \
                    &As[buf][(half) * 128 + w * 8][0]);                            \
        gload_lds16(Ab + (size_t)((half) * 128 + 64) * 1024 + (kk),                \
                    &As[buf][(half) * 128 + 64 + w * 8][0]);                       \
    } while (0)
#define STAGE_B(buf, kk)                                                           \
    do {                                                                           \
        gload_lds16(Wb + (kk), &Bs[buf][w * 8][0]);                                \
        gload_lds16(Wb + (size_t)64 * 1024 + (kk), &Bs[buf][64 + w * 8][0]);       \
    } while (0)
#define LDA(buf, mh)                                                               \
    do {                                                                           \
        _Pragma("unroll") for (int mt2 = 0; mt2 < 2; mt2++)                        \
            _Pragma("unroll") for (int ks = 0; ks < 2; ks++)                       \
                af[mt2][ks] =                                                      \
                    *(const bf16x8*)&As[buf][wr * 64 + ((mh) * 2 + mt2) * 16 + lm] \
                                        [(((quad + ks * 4) ^ (lm & 7)) * 8)];      \
    } while (0)
#define LDB(buf, nh, DST)                                                          \
    do {                                                                           \
        _Pragma("unroll") for (int nt2 = 0; nt2 < 2; nt2++)                        \
            _Pragma("unroll") for (int ks = 0; ks < 2; ks++)                       \
                DST[nt2][ks] =                                                     \
                    *(const bf16x8*)&Bs[buf][wc * 64 + ((nh) * 2 + nt2) * 16 + lm] \
                                        [(((quad + ks * 4) ^ (lm & 7)) * 8)];      \
    } while (0)
#define PHASE_MM(mh, nh, BF)                                                       \
    do {                                                                           \
        __builtin_amdgcn_s_barrier();                                              \
        asm volatile("s_waitcnt lgkmcnt(0)" ::: "memory");                         \
        __builtin_amdgcn_s_setprio(1);                                             \
        _Pragma("unroll") for (int mt2 = 0; mt2 < 2; mt2++)                        \
            _Pragma("unroll") for (int nt2 = 0; nt2 < 2; nt2++) {                  \
                f32x4 t0 = MFMA16(af[mt2][0], BF[nt2][0],                          \
                                  acc[(mh) * 2 + mt2][(nh) * 2 + nt2]);            \
                acc[(mh) * 2 + mt2][(nh) * 2 + nt2] =                              \
                    MFMA16(af[mt2][1], BF[nt2][1], t0);                            \
            }                                                                      \
        __builtin_amdgcn_s_setprio(0);                                             \
        __builtin_amdgcn_s_barrier();                                              \
    } while (0)
#define VMCNT2 asm volatile("s_waitcnt vmcnt(2)" ::: "memory")

    STAGE_A(0, 0, 0); STAGE_A(0, 1, 0);
    STAGE_B(0, 0);
    STAGE_B(1, 64);
    VMCNT2;
    __builtin_amdgcn_s_barrier();

    for (int i = 0; i < 8; i++) {
        const int t = 2 * i;
        const int k1 = (t + 1) * 64;
        const int k2 = (t + 2 < 16) ? (t + 2) * 64 : 0;
        const int k3 = (t + 3 < 16) ? (t + 3) * 64 : 0;
        // p0
        LDA(0, 0); LDB(0, 0, bfA);
        STAGE_A(1, 0, k1);
        PHASE_MM(0, 0, bfA);
        // p1
        LDB(0, 1, bfB);
        STAGE_A(1, 1, k1);
        PHASE_MM(0, 1, bfB);
        // p2
        LDA(0, 1);
        STAGE_B(0, k2);
        PHASE_MM(1, 1, bfB);
        // p3
        VMCNT2;
        PHASE_MM(1, 0, bfA);
        // p4
        LDA(1, 0); LDB(1, 0, bfA);
        STAGE_A(0, 0, k2);
        PHASE_MM(0, 0, bfA);
        // p5
        LDB(1, 1, bfB);
        STAGE_A(0, 1, k2);
        PHASE_MM(0, 1, bfB);
        // p6
        LDA(1, 1);
        STAGE_B(1, k3);
        PHASE_MM(1, 1, bfB);
        // p7
        VMCNT2;
        PHASE_MM(1, 0, bfA);
    }

    asm volatile("s_waitcnt vmcnt(0)" ::: "memory");

    bf16* qkv = (bf16*)qkvp;
#pragma unroll
    for (int mt = 0; mt < 4; mt++)
#pragma unroll
        for (int nt = 0; nt < 4; nt++) {
            f32x4 v = acc[mt][nt];
            const int gr0 = m0 + wr * 64 + mt * 16 + quad * 4;
            const int gc = n0 + wc * 64 + nt * 16 + lm;
            const int which = gc >> 10;  // 0=q 1=k 2=v
            const int h = (gc >> 6) & 15;
            const int d = gc & 63;
            const int b = gr0 >> 11, n = gr0 & 2047;
            if (which == 2) {
                short4 pk;
                pk.x = f2b(v[0]); pk.y = f2b(v[1]); pk.z = f2b(v[2]); pk.w = f2b(v[3]);
                *(short4*)&qkv[2ull * 8388608 +
                               ((size_t)((b * 16 + h) * 64 + d)) * 2048 + n] = pk;
            } else {
#pragma unroll
                for (int r = 0; r < 4; r++) {
                    float val = v[r];
                    if (which == 0) val *= QSCALE;  // fold D^-0.5 * log2(e) into Q
                    qkv[(size_t)which * 8388608 +
                        ((size_t)((b * 16 + h) * 2048 + n + r)) * 64 + d] =
                        __float2bfloat16(val);
                }
            }
        }
#undef STAGE_A
#undef STAGE_B
#undef LDA
#undef LDB
#undef PHASE_MM
#undef VMCNT2
}

// ---------- MFMA flash attention v9.1: v9 + cvt_pk P-pack with ratio cancellation ----------
// v9 (verified PASS @ 87 us) with ONE change: the P-pack uses v_cvt_pk_bf16_f32
// (2 instr for 4 values vs 4 f2b sequences), and lst is summed from the PACKED
// bf16 values (unpack = shift/mask reinterpret, bf16->f32 is a pure bit-shift).
// O = sum(Phat*v)/sum(Phat): numerator and denominator use identical Phat ->
// RTZ truncation bias cancels exactly in the ratio. Cuts ~100 VALU cyc/tile/wave
// off the serial softmax chain.
__global__ __launch_bounds__(256, 2) void attn_mfma_kernel(
    const unsigned short* __restrict__ Qg, const unsigned short* __restrict__ Kg,
    const unsigned short* __restrict__ Vtg, unsigned short* __restrict__ O) {
    __shared__ unsigned short Ks[2][64][64];   // [buf][key][d], XOR-8 swizzled
    __shared__ unsigned short Vs[2][64][64];   // [buf][d][key], XOR-8 swizzled
    __shared__ unsigned short Ps[4][4][16][64];// [wave][mt][q][key], XOR-8 swizzled
    const int tid = threadIdx.x;
    const int lane = tid & 63;
    const int w = tid >> 6;
    const int lm = lane & 15;
    const int quad = lane >> 4;
    const int bh = blockIdx.x & 63;        // same bh -> same XCD (id mod 8 fixed)
    const int n0 = (blockIdx.x >> 6) * 256;
    const size_t base = (size_t)bh * (2048 * 64);

    // Q as B-operand (pre-scaled QSCALE), resident all tiles; 64 q-rows per wave
    bf16x8 qf[4][2];
#pragma unroll
    for (int mt = 0; mt < 4; mt++)
#pragma unroll
        for (int ks = 0; ks < 2; ks++)
            qf[mt][ks] = *(const bf16x8*)&Qg[base +
                                            (size_t)(n0 + w * 64 + mt * 16 + lm) * 64 +
                                            ks * 32 + quad * 8];

    f32x4 accO[4][4] = {};
    float lst[4] = {0.f, 0.f, 0.f, 0.f};

    const int sr = lane >> 3;
    const int sg = (lane & 7) ^ sr;

    // prologue: stage K(0), V(0) into buf 0
#pragma unroll
    for (int j = 0; j < 2; j++) {
        const int row = w * 16 + j * 8 + sr;
        gload_lds16(&Vtg[base + (size_t)row * 2048 + sg * 8], &Vs[0][w * 16 + j * 8][0]);
        gload_lds16(&Kg[base + (size_t)row * 64 + sg * 8], &Ks[0][w * 16 + j * 8][0]);
    }

    int kb = 0;
    for (int t = 0; t < 32; t++) {
        // own DMA(t) landed (issued a full tile ago except t=0), then barrier:
        // all waves' DMA(t) visible AND all t-1 buf^1 reads complete.
        asm volatile("s_waitcnt vmcnt(0)" ::: "memory");
        __builtin_amdgcn_s_barrier();

        if (t + 1 < 32) {
            const int k0n = (t + 1) * 64;
#pragma unroll
            for (int j = 0; j < 2; j++) {
                const int row = w * 16 + j * 8 + sr;
                gload_lds16(&Vtg[base + (size_t)row * 2048 + k0n + sg * 8],
                            &Vs[kb ^ 1][w * 16 + j * 8][0]);
                gload_lds16(&Kg[base + (size_t)(k0n + row) * 64 + sg * 8],
                            &Ks[kb ^ 1][w * 16 + j * 8][0]);
            }
        }

        // ---- compute on buf kb: NO fences below (full pipe overlap) ----
        bf16x8 kbf[4][2];
#pragma unroll
        for (int kt = 0; kt < 4; kt++)
#pragma unroll
            for (int ks = 0; ks < 2; ks++)
                kbf[kt][ks] = *(const bf16x8*)&Ks[kb][kt * 16 + lm]
                                                 [(((ks * 4 + quad) ^ (lm & 7)) * 8)];

        // per-mt: S^T = K·Q^T (8 MFMA) then exp2 + cvt_pk pack + P^T store
#pragma unroll
        for (int mt = 0; mt < 4; mt++) {
            f32x4 s[4];
            __builtin_amdgcn_s_setprio(1);
#pragma unroll
            for (int kt = 0; kt < 4; kt++) {
                f32x4 z = {};
                z = MFMA16(kbf[kt][0], qf[mt][0], z);
                s[kt] = MFMA16(kbf[kt][1], qf[mt][1], z);
            }
            __builtin_amdgcn_s_setprio(0);
            float ps = 0.f;
#pragma unroll
            for (int kt = 0; kt < 4; kt++) {
                const float p0 = exp2_fast(s[kt][0]);
                const float p1 = exp2_fast(s[kt][1]);
                const float p2 = exp2_fast(s[kt][2]);
                const float p3 = exp2_fast(s[kt][3]);
                const u32 w0 = cvt_pk_bf16(p0, p1);   // {lo:p0, hi:p1} RTZ
                const u32 w1 = cvt_pk_bf16(p2, p3);
                // lst from the PACKED values (bf16->f32 = bit shift) -> exact
                // ratio cancellation of the truncation bias in O = num/den.
                ps += (__uint_as_float(w0 << 16) +
                       __uint_as_float(w0 & 0xffff0000u)) +
                      (__uint_as_float(w1 << 16) +
                       __uint_as_float(w1 & 0xffff0000u));
                uint2 pk2;
                pk2.x = w0; pk2.y = w1;
                const int g = kt * 2 + (quad >> 1);
                *(uint2*)&Ps[w][mt][lm][((g ^ (lm & 7)) * 8) + (quad & 1) * 4] = pk2;
            }
            lst[mt] += ps;
        }

        // PV: O^T += V^T·P^T (Vs[kb] visible since tile-top barrier; Ps wave-private)
        bf16x8 vbf[4][2];
#pragma unroll
        for (int nt = 0; nt < 4; nt++)
#pragma unroll
            for (int ks = 0; ks < 2; ks++)
                vbf[nt][ks] = *(const bf16x8*)&Vs[kb][nt * 16 + lm]
                                                 [(((ks * 4 + quad) ^ (lm & 7)) * 8)];
#pragma unroll
        for (int mt = 0; mt < 4; mt++) {
            bf16x8 pb0 = *(const bf16x8*)&Ps[w][mt][lm][(((quad) ^ (lm & 7)) * 8)];
            bf16x8 pb1 = *(const bf16x8*)&Ps[w][mt][lm][(((4 + quad) ^ (lm & 7)) * 8)];
            __builtin_amdgcn_s_setprio(1);
#pragma unroll
            for (int nt = 0; nt < 4; nt++) {
                f32x4 a = MFMA16(vbf[nt][0], pb0, accO[mt][nt]);
                accO[mt][nt] = MFMA16(vbf[nt][1], pb1, a);
            }
            __builtin_amdgcn_s_setprio(0);
        }

        kb ^= 1;
    }

#pragma unroll
    for (int mt = 0; mt < 4; mt++) {
        lst[mt] += __shfl_xor(lst[mt], 16);
        lst[mt] += __shfl_xor(lst[mt], 32);
    }

    const int b = bh >> 4, h = bh & 15;
#pragma unroll
    for (int mt = 0; mt < 4; mt++) {
        const float inv = 1.0f / lst[mt];
        const int n = n0 + w * 64 + mt * 16 + lm;
#pragma unroll
        for (int nt = 0; nt < 4; nt++) {
            short4 pk;
            pk.x = f2b(accO[mt][nt][0] * inv);
            pk.y = f2b(accO[mt][nt][1] * inv);
            pk.z = f2b(accO[mt][nt][2] * inv);
            pk.w = f2b(accO[mt][nt][3] * inv);
            *(short4*)&O[((size_t)(b * 2048 + n)) * 1024 + h * 64 + nt * 16 + quad * 4] = pk;
        }
    }
}

extern "C" void kernel_launch(void* const* d_in, const int* in_sizes, int n_in,
                              void* d_out, int out_size, void* d_ws, size_t ws_size,
                              hipStream_t stream) {
    const float* x = (const float*)d_in[0];      // [4,2048,1024] fp32
    const float* w_qkv = (const float*)d_in[1];  // [3072,1024] fp32
    const float* w_out = (const float*)d_in[2];  // [1024,1024] fp32
    float* out = (float*)d_out;                  // [4,2048,1024] fp32

    unsigned short* qkvb = (unsigned short*)d_ws;
    unsigned short* xb = qkvb + 3ull * 8388608;
    unsigned short* wqkvb = xb + 8388608;
    unsigned short* woutb = wqkvb + 3145728;

    // 0) fp32 -> bf16, single launch
    cvt3_kernel<<<6144, 256, 0, stream>>>(x, w_qkv, w_out, xb, wqkvb, woutb);
    // 1) QKV projection: 256x128 8-phase, 768 blocks = 3 exact rounds
    gemm256x128_qkv_kernel<<<768, 512, 0, stream>>>(xb, wqkvb, qkvb);
    // 2) MFMA flash attention v9.1 (cvt_pk + ratio cancellation) -> bf16 attn_out
    attn_mfma_kernel<<<512, 256, 0, stream>>>(qkvb, qkvb + 8388608,
                                              qkvb + 2 * 8388608, xb);
    // 3) output projection (m97-structure) -> fp32 out
    gemm128_kernel<1><<<dim3(8, 64), 256, 0, stream>>>(xb, woutb, out);
}

// Round 12
// 257.675 us; speedup vs baseline: 1.0112x; 1.0112x over previous
//
#include <hip/hip_runtime.h>
#include <hip/hip_bf16.h>

typedef short bf16x8 __attribute__((ext_vector_type(8)));
typedef float f32x4 __attribute__((ext_vector_type(4)));
using bf16 = __hip_bfloat16;

#define MFMA16(a, b, c) __builtin_amdgcn_mfma_f32_16x16x32_bf16(a, b, c, 0, 0, 0)

typedef unsigned int u32;
typedef u32 __attribute__((address_space(1))) global_u32;
typedef u32 __attribute__((address_space(3))) lds_u32;

__device__ __forceinline__ void gload_lds16(const unsigned short* g, unsigned short* l) {
    // async 16B/lane global->LDS DMA; LDS dest = wave-uniform base + lane*16
    __builtin_amdgcn_global_load_lds((const global_u32*)g, (lds_u32*)l, 16, 0, 0);
}

__device__ __forceinline__ short f2b(float f) {
    __hip_bfloat16 h = __float2bfloat16(f);  // RNE
    return *reinterpret_cast<short*>(&h);
}

__device__ __forceinline__ float exp2_fast(float x) {
    float r;
    asm("v_exp_f32 %0, %1" : "=v"(r) : "v"(x));
    return r;
}

// Q pre-scale: D^-0.5 * log2(e); attn then uses exp2 -> saves one v_mul per score
#define QSCALE 0.18033688011112042f

// ---------- fp32 -> bf16 convert, all three inputs in ONE launch ----------
__global__ __launch_bounds__(256) void cvt3_kernel(const float* __restrict__ x,
                                                   const float* __restrict__ wq,
                                                   const float* __restrict__ wo,
                                                   unsigned short* __restrict__ xb,
                                                   unsigned short* __restrict__ wqb,
                                                   unsigned short* __restrict__ wob) {
    const int id = blockIdx.x;
    const float* src;
    unsigned short* dst;
    size_t off;
    if (id < 4096) {
        src = x; dst = xb; off = (size_t)id * 2048;
    } else if (id < 5632) {
        src = wq; dst = wqb; off = (size_t)(id - 4096) * 2048;
    } else {
        src = wo; dst = wob; off = (size_t)(id - 5632) * 2048;
    }
    const size_t i = off + (size_t)threadIdx.x * 8;
    float4 v0 = *(const float4*)(src + i);
    float4 v1 = *(const float4*)(src + i + 4);
    bf16x8 o;
    o[0] = f2b(v0.x); o[1] = f2b(v0.y); o[2] = f2b(v0.z); o[3] = f2b(v0.w);
    o[4] = f2b(v1.x); o[5] = f2b(v1.y); o[6] = f2b(v1.z); o[7] = f2b(v1.w);
    *(bf16x8*)(dst + i) = o;
}

// ---------- m97-structure bf16 GEMM (kept for out-projection, MODE 1) ----------
template <int MODE>
__global__ __launch_bounds__(256) void gemm128_kernel(const unsigned short* __restrict__ A,
                                                      const unsigned short* __restrict__ W,
                                                      void* __restrict__ outp) {
    __shared__ unsigned short As[128][64];
    __shared__ unsigned short Ws[128][64];
    const int tid = threadIdx.x;
    const int lane = tid & 63;
    const int w = tid >> 6;
    const int wr = w >> 1, wc = w & 1;
    const int lm = lane & 15, quad = lane >> 4;
    const int m0 = blockIdx.y * 128, n0 = blockIdx.x * 128;

    const int srow8 = lane >> 3;
    const int skg = (lane & 7) ^ srow8;
    const unsigned short* Ag = A + (size_t)(m0 + w * 32 + srow8) * 1024 + skg * 8;
    const unsigned short* Wg = W + (size_t)(n0 + w * 32 + srow8) * 1024 + skg * 8;

    f32x4 acc[4][4] = {};

    for (int k0 = 0; k0 < 1024; k0 += 64) {
        __syncthreads();
#pragma unroll
        for (int j = 0; j < 4; j++) {
            gload_lds16(Ag + j * (8 * 1024), &As[w * 32 + j * 8][0]);
            gload_lds16(Wg + j * (8 * 1024), &Ws[w * 32 + j * 8][0]);
        }
        Ag += 64;
        Wg += 64;
        __syncthreads();
#pragma unroll
        for (int ks = 0; ks < 2; ks++) {
            const int swz = ((quad + ks * 4) ^ (lm & 7)) * 8;
            bf16x8 af[4], bf[4];
#pragma unroll
            for (int mt = 0; mt < 4; mt++)
                af[mt] = *(const bf16x8*)&As[wr * 64 + mt * 16 + lm][swz];
#pragma unroll
            for (int nt = 0; nt < 4; nt++)
                bf[nt] = *(const bf16x8*)&Ws[wc * 64 + nt * 16 + lm][swz];
#pragma unroll
            for (int mt = 0; mt < 4; mt++)
#pragma unroll
                for (int nt = 0; nt < 4; nt++)
                    acc[mt][nt] = MFMA16(af[mt], bf[nt], acc[mt][nt]);
        }
    }

#pragma unroll
    for (int mt = 0; mt < 4; mt++)
#pragma unroll
        for (int nt = 0; nt < 4; nt++) {
            f32x4 v = acc[mt][nt];
            const int gr0 = m0 + wr * 64 + mt * 16 + quad * 4;
            const int gc = n0 + wc * 64 + nt * 16 + lm;
            if (MODE == 2) {
                bf16* qkv = (bf16*)outp;
                const int which = gc >> 10;
                const int h = (gc >> 6) & 15;
                const int d = gc & 63;
                const int b = gr0 >> 11, n = gr0 & 2047;
                if (which == 2) {
                    short4 pk;
                    pk.x = f2b(v[0]); pk.y = f2b(v[1]); pk.z = f2b(v[2]); pk.w = f2b(v[3]);
                    *(short4*)&qkv[2ull * 8388608 +
                                   ((size_t)((b * 16 + h) * 64 + d)) * 2048 + n] = pk;
                } else {
#pragma unroll
                    for (int r = 0; r < 4; r++) {
                        float val = v[r];
                        if (which == 0) val *= QSCALE;
                        qkv[(size_t)which * 8388608 +
                            ((size_t)((b * 16 + h) * 2048 + n + r)) * 64 + d] =
                            __float2bfloat16(val);
                    }
                }
            } else {
                float* o = (float*)outp;
#pragma unroll
                for (int r = 0; r < 4; r++) o[(size_t)(gr0 + r) * 1024 + gc] = v[r];
            }
        }
}

// ---------- 256x128 8-phase bf16 GEMM for the QKV projection (R2, passed) ----------
__global__ __launch_bounds__(512, 2) void gemm256x128_qkv_kernel(
    const unsigned short* __restrict__ A,   // [8192,1024] bf16
    const unsigned short* __restrict__ W,   // [3072,1024] bf16
    unsigned short* __restrict__ qkvp) {
    __shared__ unsigned short As[2][256][64];
    __shared__ unsigned short Bs[2][128][64];
    const int tid = threadIdx.x;
    const int lane = tid & 63;
    const int w = tid >> 6;               // 0..7
    const int wr = w >> 1, wc = w & 1;    // 4M x 2N wave grid
    const int lm = lane & 15, quad = lane >> 4;

    const int id = blockIdx.x;
    const int xs = (id & 7) * 96 + (id >> 3);
    const int n0 = (xs % 24) * 128;
    const int m0 = (xs / 24) * 256;

    const int sr = lane >> 3;
    const int sg = (lane & 7) ^ sr;
    const unsigned short* Ab = A + (size_t)(m0 + w * 8 + sr) * 1024 + sg * 8;
    const unsigned short* Wb = W + (size_t)(n0 + w * 8 + sr) * 1024 + sg * 8;

    f32x4 acc[4][4] = {};
    bf16x8 af[2][2];
    bf16x8 bfA[2][2];
    bf16x8 bfB[2][2];

#define STAGE_A(buf, half, kk)                                                     \
    do {                                                                           \
        gload_lds16(Ab + (size_t)((half) * 128) * 1024 + (kk),                     \
                    &As[buf][(half) * 128 + w * 8][0]);                            \
        gload_lds16(Ab + (size_t)((half) * 128 + 64) * 1024 + (kk),                \
                    &As[buf][(half) * 128 + 64 + w * 8][0]);                       \
    } while (0)
#define STAGE_B(buf, kk)                                                           \
    do {                                                                           \
        gload_lds16(Wb + (kk), &Bs[buf][w * 8][0]);                                \
        gload_lds16(Wb + (size_t)64 * 1024 + (kk), &Bs[buf][64 + w * 8][0]);       \
    } while (0)
#define LDA(buf, mh)                                                               \
    do {                                                                           \
        _Pragma("unroll") for (int mt2 = 0; mt2 < 2; mt2++)                        \
            _Pragma("unroll") for (int ks = 0; ks < 2; ks++)                       \
                af[mt2][ks] =                                                      \
                    *(const bf16x8*)&As[buf][wr * 64 + ((mh) * 2 + mt2) * 16 + lm] \
                                        [(((quad + ks * 4) ^ (lm & 7)) * 8)];      \
    } while (0)
#define LDB(buf, nh, DST)                                                          \
    do {                                                                           \
        _Pragma("unroll") for (int nt2 = 0; nt2 < 2; nt2++)                        \
            _Pragma("unroll") for (int ks = 0; ks < 2; ks++)                       \
                DST[nt2][ks] =                                                     \
                    *(const bf16x8*)&Bs[buf][wc * 64 + ((nh) * 2 + nt2) * 16 + lm] \
                                        [(((quad + ks * 4) ^ (lm & 7)) * 8)];      \
    } while (0)
#define PHASE_MM(mh, nh, BF)                                                       \
    do {                                                                           \
        __builtin_amdgcn_s_barrier();                                              \
        asm volatile("s_waitcnt lgkmcnt(0)" ::: "memory");                         \
        __builtin_amdgcn_s_setprio(1);                                             \
        _Pragma("unroll") for (int mt2 = 0; mt2 < 2; mt2++)                        \
            _Pragma("unroll") for (int nt2 = 0; nt2 < 2; nt2++) {                  \
                f32x4 t0 = MFMA16(af[mt2][0], BF[nt2][0],                          \
                                  acc[(mh) * 2 + mt2][(nh) * 2 + nt2]);            \
                acc[(mh) * 2 + mt2][(nh) * 2 + nt2] =                              \
                    MFMA16(af[mt2][1], BF[nt2][1], t0);                            \
            }                                                                      \
        __builtin_amdgcn_s_setprio(0);                                             \
        __builtin_amdgcn_s_barrier();                                              \
    } while (0)
#define VMCNT2 asm volatile("s_waitcnt vmcnt(2)" ::: "memory")

    STAGE_A(0, 0, 0); STAGE_A(0, 1, 0);
    STAGE_B(0, 0);
    STAGE_B(1, 64);
    VMCNT2;
    __builtin_amdgcn_s_barrier();

    for (int i = 0; i < 8; i++) {
        const int t = 2 * i;
        const int k1 = (t + 1) * 64;
        const int k2 = (t + 2 < 16) ? (t + 2) * 64 : 0;
        const int k3 = (t + 3 < 16) ? (t + 3) * 64 : 0;
        // p0
        LDA(0, 0); LDB(0, 0, bfA);
        STAGE_A(1, 0, k1);
        PHASE_MM(0, 0, bfA);
        // p1
        LDB(0, 1, bfB);
        STAGE_A(1, 1, k1);
        PHASE_MM(0, 1, bfB);
        // p2
        LDA(0, 1);
        STAGE_B(0, k2);
        PHASE_MM(1, 1, bfB);
        // p3
        VMCNT2;
        PHASE_MM(1, 0, bfA);
        // p4
        LDA(1, 0); LDB(1, 0, bfA);
        STAGE_A(0, 0, k2);
        PHASE_MM(0, 0, bfA);
        // p5
        LDB(1, 1, bfB);
        STAGE_A(0, 1, k2);
        PHASE_MM(0, 1, bfB);
        // p6
        LDA(1, 1);
        STAGE_B(1, k3);
        PHASE_MM(1, 1, bfB);
        // p7
        VMCNT2;
        PHASE_MM(1, 0, bfA);
    }

    asm volatile("s_waitcnt vmcnt(0)" ::: "memory");

    bf16* qkv = (bf16*)qkvp;
#pragma unroll
    for (int mt = 0; mt < 4; mt++)
#pragma unroll
        for (int nt = 0; nt < 4; nt++) {
            f32x4 v = acc[mt][nt];
            const int gr0 = m0 + wr * 64 + mt * 16 + quad * 4;
            const int gc = n0 + wc * 64 + nt * 16 + lm;
            const int which = gc >> 10;  // 0=q 1=k 2=v
            const int h = (gc >> 6) & 15;
            const int d = gc & 63;
            const int b = gr0 >> 11, n = gr0 & 2047;
            if (which == 2) {
                short4 pk;
                pk.x = f2b(v[0]); pk.y = f2b(v[1]); pk.z = f2b(v[2]); pk.w = f2b(v[3]);
                *(short4*)&qkv[2ull * 8388608 +
                               ((size_t)((b * 16 + h) * 64 + d)) * 2048 + n] = pk;
            } else {
#pragma unroll
                for (int r = 0; r < 4; r++) {
                    float val = v[r];
                    if (which == 0) val *= QSCALE;  // fold D^-0.5 * log2(e) into Q
                    qkv[(size_t)which * 8388608 +
                        ((size_t)((b * 16 + h) * 2048 + n + r)) * 64 + d] =
                        __float2bfloat16(val);
                }
            }
        }
#undef STAGE_A
#undef STAGE_B
#undef LDA
#undef LDB
#undef PHASE_MM
#undef VMCNT2
}

// ---------- MFMA flash attention v9 (R9 verbatim, verified PASS @ 87 us) ----------
// ONE barrier per tile; K/V double-buffered; DMA(t+1) issued right after barrier.
// !!! The s_setprio pairs in this loop are LOAD-BEARING (R11 lesson): removing
// them broke numerics (absmax 7.7e-2). Per guide rule #18, hipcc sinks/hoists
// register-only MFMA and lgkmcnt drains across inline-asm fences; the setprio
// side-effect anchors pin the schedule so no wave crosses the tile-top barrier
// with outstanding ds_reads of the buffer the next DMA overwrites. Do not remove
// without adding explicit sched_barrier(0) fencing designed for it.
__global__ __launch_bounds__(256, 2) void attn_mfma_kernel(
    const unsigned short* __restrict__ Qg, const unsigned short* __restrict__ Kg,
    const unsigned short* __restrict__ Vtg, unsigned short* __restrict__ O) {
    __shared__ unsigned short Ks[2][64][64];   // [buf][key][d], XOR-8 swizzled
    __shared__ unsigned short Vs[2][64][64];   // [buf][d][key], XOR-8 swizzled
    __shared__ unsigned short Ps[4][4][16][64];// [wave][mt][q][key], XOR-8 swizzled
    const int tid = threadIdx.x;
    const int lane = tid & 63;
    const int w = tid >> 6;
    const int lm = lane & 15;
    const int quad = lane >> 4;
    const int bh = blockIdx.x & 63;        // same bh -> same XCD (id mod 8 fixed)
    const int n0 = (blockIdx.x >> 6) * 256;
    const size_t base = (size_t)bh * (2048 * 64);

    // Q as B-operand (pre-scaled QSCALE), resident all tiles; 64 q-rows per wave
    bf16x8 qf[4][2];
#pragma unroll
    for (int mt = 0; mt < 4; mt++)
#pragma unroll
        for (int ks = 0; ks < 2; ks++)
            qf[mt][ks] = *(const bf16x8*)&Qg[base +
                                            (size_t)(n0 + w * 64 + mt * 16 + lm) * 64 +
                                            ks * 32 + quad * 8];

    f32x4 accO[4][4] = {};
    float lst[4] = {0.f, 0.f, 0.f, 0.f};

    const int sr = lane >> 3;
    const int sg = (lane & 7) ^ sr;

    // prologue: stage K(0), V(0) into buf 0
#pragma unroll
    for (int j = 0; j < 2; j++) {
        const int row = w * 16 + j * 8 + sr;
        gload_lds16(&Vtg[base + (size_t)row * 2048 + sg * 8], &Vs[0][w * 16 + j * 8][0]);
        gload_lds16(&Kg[base + (size_t)row * 64 + sg * 8], &Ks[0][w * 16 + j * 8][0]);
    }

    int kb = 0;
    for (int t = 0; t < 32; t++) {
        // own DMA(t) landed (issued a full tile ago except t=0), then barrier:
        // all waves' DMA(t) visible AND all t-1 buf^1 reads complete.
        asm volatile("s_waitcnt vmcnt(0)" ::: "memory");
        __builtin_amdgcn_s_barrier();

        if (t + 1 < 32) {
            const int k0n = (t + 1) * 64;
#pragma unroll
            for (int j = 0; j < 2; j++) {
                const int row = w * 16 + j * 8 + sr;
                gload_lds16(&Vtg[base + (size_t)row * 2048 + k0n + sg * 8],
                            &Vs[kb ^ 1][w * 16 + j * 8][0]);
                gload_lds16(&Kg[base + (size_t)(k0n + row) * 64 + sg * 8],
                            &Ks[kb ^ 1][w * 16 + j * 8][0]);
            }
        }

        // ---- compute on buf kb ----
        bf16x8 kbf[4][2];
#pragma unroll
        for (int kt = 0; kt < 4; kt++)
#pragma unroll
            for (int ks = 0; ks < 2; ks++)
                kbf[kt][ks] = *(const bf16x8*)&Ks[kb][kt * 16 + lm]
                                                 [(((ks * 4 + quad) ^ (lm & 7)) * 8)];

        // per-mt: S^T = K·Q^T (8 MFMA) then exp2 + P^T store (s transient)
#pragma unroll
        for (int mt = 0; mt < 4; mt++) {
            f32x4 s[4];
            __builtin_amdgcn_s_setprio(1);
#pragma unroll
            for (int kt = 0; kt < 4; kt++) {
                f32x4 z = {};
                z = MFMA16(kbf[kt][0], qf[mt][0], z);
                s[kt] = MFMA16(kbf[kt][1], qf[mt][1], z);
            }
            __builtin_amdgcn_s_setprio(0);
            float ps = 0.f;
#pragma unroll
            for (int kt = 0; kt < 4; kt++) {
                const float p0 = exp2_fast(s[kt][0]);
                const float p1 = exp2_fast(s[kt][1]);
                const float p2 = exp2_fast(s[kt][2]);
                const float p3 = exp2_fast(s[kt][3]);
                ps += (p0 + p1) + (p2 + p3);
                short4 pk;
                pk.x = f2b(p0); pk.y = f2b(p1); pk.z = f2b(p2); pk.w = f2b(p3);
                const int g = kt * 2 + (quad >> 1);
                *(short4*)&Ps[w][mt][lm][((g ^ (lm & 7)) * 8) + (quad & 1) * 4] = pk;
            }
            lst[mt] += ps;
        }

        // PV: O^T += V^T·P^T (Vs[kb] visible since tile-top barrier; Ps wave-private)
        bf16x8 vbf[4][2];
#pragma unroll
        for (int nt = 0; nt < 4; nt++)
#pragma unroll
            for (int ks = 0; ks < 2; ks++)
                vbf[nt][ks] = *(const bf16x8*)&Vs[kb][nt * 16 + lm]
                                                 [(((ks * 4 + quad) ^ (lm & 7)) * 8)];
#pragma unroll
        for (int mt = 0; mt < 4; mt++) {
            bf16x8 pb0 = *(const bf16x8*)&Ps[w][mt][lm][(((quad) ^ (lm & 7)) * 8)];
            bf16x8 pb1 = *(const bf16x8*)&Ps[w][mt][lm][(((4 + quad) ^ (lm & 7)) * 8)];
            __builtin_amdgcn_s_setprio(1);
#pragma unroll
            for (int nt = 0; nt < 4; nt++) {
                f32x4 a = MFMA16(vbf[nt][0], pb0, accO[mt][nt]);
                accO[mt][nt] = MFMA16(vbf[nt][1], pb1, a);
            }
            __builtin_amdgcn_s_setprio(0);
        }

        kb ^= 1;
    }

#pragma unroll
    for (int mt = 0; mt < 4; mt++) {
        lst[mt] += __shfl_xor(lst[mt], 16);
        lst[mt] += __shfl_xor(lst[mt], 32);
    }

    const int b = bh >> 4, h = bh & 15;
#pragma unroll
    for (int mt = 0; mt < 4; mt++) {
        const float inv = 1.0f / lst[mt];
        const int n = n0 + w * 64 + mt * 16 + lm;
#pragma unroll
        for (int nt = 0; nt < 4; nt++) {
            short4 pk;
            pk.x = f2b(accO[mt][nt][0] * inv);
            pk.y = f2b(accO[mt][nt][1] * inv);
            pk.z = f2b(accO[mt][nt][2] * inv);
            pk.w = f2b(accO[mt][nt][3] * inv);
            *(short4*)&O[((size_t)(b * 2048 + n)) * 1024 + h * 64 + nt * 16 + quad * 4] = pk;
        }
    }
}

extern "C" void kernel_launch(void* const* d_in, const int* in_sizes, int n_in,
                              void* d_out, int out_size, void* d_ws, size_t ws_size,
                              hipStream_t stream) {
    const float* x = (const float*)d_in[0];      // [4,2048,1024] fp32
    const float* w_qkv = (const float*)d_in[1];  // [3072,1024] fp32
    const float* w_out = (const float*)d_in[2];  // [1024,1024] fp32
    float* out = (float*)d_out;                  // [4,2048,1024] fp32

    unsigned short* qkvb = (unsigned short*)d_ws;
    unsigned short* xb = qkvb + 3ull * 8388608;
    unsigned short* wqkvb = xb + 8388608;
    unsigned short* woutb = wqkvb + 3145728;

    // 0) fp32 -> bf16, single launch
    cvt3_kernel<<<6144, 256, 0, stream>>>(x, w_qkv, w_out, xb, wqkvb, woutb);
    // 1) QKV projection: 256x128 8-phase, 768 blocks = 3 exact rounds
    gemm256x128_qkv_kernel<<<768, 512, 0, stream>>>(xb, wqkvb, qkvb);
    // 2) MFMA flash attention v9 (1 barrier/tile) -> bf16 attn_out
    attn_mfma_kernel<<<512, 256, 0, stream>>>(qkvb, qkvb + 8388608,
                                              qkvb + 2 * 8388608, xb);
    // 3) output projection (m97-structure) -> fp32 out
    gemm128_kernel<1><<<dim3(8, 64), 256, 0, stream>>>(xb, woutb, out);
}

// Round 13
// 251.397 us; speedup vs baseline: 1.0365x; 1.0250x over previous
//
#include <hip/hip_runtime.h>
#include <hip/hip_bf16.h>

typedef short bf16x8 __attribute__((ext_vector_type(8)));
typedef float f32x4 __attribute__((ext_vector_type(4)));
using bf16 = __hip_bfloat16;

#define MFMA16(a, b, c) __builtin_amdgcn_mfma_f32_16x16x32_bf16(a, b, c, 0, 0, 0)

typedef unsigned int u32;
typedef u32 __attribute__((address_space(1))) global_u32;
typedef u32 __attribute__((address_space(3))) lds_u32;

__device__ __forceinline__ void gload_lds16(const unsigned short* g, unsigned short* l) {
    // async 16B/lane global->LDS DMA; LDS dest = wave-uniform base + lane*16
    __builtin_amdgcn_global_load_lds((const global_u32*)g, (lds_u32*)l, 16, 0, 0);
}

__device__ __forceinline__ short f2b(float f) {
    __hip_bfloat16 h = __float2bfloat16(f);  // RNE
    return *reinterpret_cast<short*>(&h);
}

__device__ __forceinline__ float exp2_fast(float x) {
    float r;
    asm("v_exp_f32 %0, %1" : "=v"(r) : "v"(x));
    return r;
}

// Q pre-scale: D^-0.5 * log2(e); attn then uses exp2 -> saves one v_mul per score
#define QSCALE 0.18033688011112042f

// ---------- fp32 -> bf16 convert, all three inputs in ONE launch ----------
__global__ __launch_bounds__(256) void cvt3_kernel(const float* __restrict__ x,
                                                   const float* __restrict__ wq,
                                                   const float* __restrict__ wo,
                                                   unsigned short* __restrict__ xb,
                                                   unsigned short* __restrict__ wqb,
                                                   unsigned short* __restrict__ wob) {
    const int id = blockIdx.x;
    const float* src;
    unsigned short* dst;
    size_t off;
    if (id < 4096) {
        src = x; dst = xb; off = (size_t)id * 2048;
    } else if (id < 5632) {
        src = wq; dst = wqb; off = (size_t)(id - 4096) * 2048;
    } else {
        src = wo; dst = wob; off = (size_t)(id - 5632) * 2048;
    }
    const size_t i = off + (size_t)threadIdx.x * 8;
    float4 v0 = *(const float4*)(src + i);
    float4 v1 = *(const float4*)(src + i + 4);
    bf16x8 o;
    o[0] = f2b(v0.x); o[1] = f2b(v0.y); o[2] = f2b(v0.z); o[3] = f2b(v0.w);
    o[4] = f2b(v1.x); o[5] = f2b(v1.y); o[6] = f2b(v1.z); o[7] = f2b(v1.w);
    *(bf16x8*)(dst + i) = o;
}

// ---------- 256x128 8-phase bf16 GEMM (R2-verified K-loop, templated epilogue) ----------
// MODE 2: QKV scatter (Q scaled, K row-major, V transposed). MODE 1: fp32 row-major.
// NTN = N-tiles (N/128). Grid = 32*NTN blocks; bijective XCD swizzle requires
// (32*NTN) % 8 == 0 (QKV: NTN=24 -> 768 blocks = 3 rounds; outproj: NTN=8 ->
// 256 blocks = EXACTLY 1 block/CU, one perfect round).
template <int MODE, int NTN>
__global__ __launch_bounds__(512, 2) void gemm256x128_kernel(
    const unsigned short* __restrict__ A,   // [M,1024] bf16
    const unsigned short* __restrict__ W,   // [N,1024] bf16
    void* __restrict__ outp) {
    __shared__ unsigned short As[2][256][64];
    __shared__ unsigned short Bs[2][128][64];
    const int tid = threadIdx.x;
    const int lane = tid & 63;
    const int w = tid >> 6;               // 0..7
    const int wr = w >> 1, wc = w & 1;    // 4M x 2N wave grid
    const int lm = lane & 15, quad = lane >> 4;

    constexpr int TPX = 4 * NTN;          // tiles per XCD = (32*NTN)/8
    const int id = blockIdx.x;
    const int xs = (id & 7) * TPX + (id >> 3);
    const int n0 = (xs % NTN) * 128;
    const int m0 = (xs / NTN) * 256;

    const int sr = lane >> 3;
    const int sg = (lane & 7) ^ sr;
    const unsigned short* Ab = A + (size_t)(m0 + w * 8 + sr) * 1024 + sg * 8;
    const unsigned short* Wb = W + (size_t)(n0 + w * 8 + sr) * 1024 + sg * 8;

    f32x4 acc[4][4] = {};
    bf16x8 af[2][2];
    bf16x8 bfA[2][2];
    bf16x8 bfB[2][2];

#define STAGE_A(buf, half, kk)                                                     \
    do {                                                                           \
        gload_lds16(Ab + (size_t)((half) * 128) * 1024 + (kk),                     \
                    &As[buf][(half) * 128 + w * 8][0]);                            \
        gload_lds16(Ab + (size_t)((half) * 128 + 64) * 1024 + (kk),                \
                    &As[buf][(half) * 128 + 64 + w * 8][0]);                       \
    } while (0)
#define STAGE_B(buf, kk)                                                           \
    do {                                                                           \
        gload_lds16(Wb + (kk), &Bs[buf][w * 8][0]);                                \
        gload_lds16(Wb + (size_t)64 * 1024 + (kk), &Bs[buf][64 + w * 8][0]);       \
    } while (0)
#define LDA(buf, mh)                                                               \
    do {                                                                           \
        _Pragma("unroll") for (int mt2 = 0; mt2 < 2; mt2++)                        \
            _Pragma("unroll") for (int ks = 0; ks < 2; ks++)                       \
                af[mt2][ks] =                                                      \
                    *(const bf16x8*)&As[buf][wr * 64 + ((mh) * 2 + mt2) * 16 + lm] \
                                        [(((quad + ks * 4) ^ (lm & 7)) * 8)];      \
    } while (0)
#define LDB(buf, nh, DST)                                                          \
    do {                                                                           \
        _Pragma("unroll") for (int nt2 = 0; nt2 < 2; nt2++)                        \
            _Pragma("unroll") for (int ks = 0; ks < 2; ks++)                       \
                DST[nt2][ks] =                                                     \
                    *(const bf16x8*)&Bs[buf][wc * 64 + ((nh) * 2 + nt2) * 16 + lm] \
                                        [(((quad + ks * 4) ^ (lm & 7)) * 8)];      \
    } while (0)
#define PHASE_MM(mh, nh, BF)                                                       \
    do {                                                                           \
        __builtin_amdgcn_s_barrier();                                              \
        asm volatile("s_waitcnt lgkmcnt(0)" ::: "memory");                         \
        __builtin_amdgcn_s_setprio(1);                                             \
        _Pragma("unroll") for (int mt2 = 0; mt2 < 2; mt2++)                        \
            _Pragma("unroll") for (int nt2 = 0; nt2 < 2; nt2++) {                  \
                f32x4 t0 = MFMA16(af[mt2][0], BF[nt2][0],                          \
                                  acc[(mh) * 2 + mt2][(nh) * 2 + nt2]);            \
                acc[(mh) * 2 + mt2][(nh) * 2 + nt2] =                              \
                    MFMA16(af[mt2][1], BF[nt2][1], t0);                            \
            }                                                                      \
        __builtin_amdgcn_s_setprio(0);                                             \
        __builtin_amdgcn_s_barrier();                                              \
    } while (0)
#define VMCNT2 asm volatile("s_waitcnt vmcnt(2)" ::: "memory")

    STAGE_A(0, 0, 0); STAGE_A(0, 1, 0);
    STAGE_B(0, 0);
    STAGE_B(1, 64);
    VMCNT2;
    __builtin_amdgcn_s_barrier();

    for (int i = 0; i < 8; i++) {
        const int t = 2 * i;
        const int k1 = (t + 1) * 64;
        const int k2 = (t + 2 < 16) ? (t + 2) * 64 : 0;
        const int k3 = (t + 3 < 16) ? (t + 3) * 64 : 0;
        // p0
        LDA(0, 0); LDB(0, 0, bfA);
        STAGE_A(1, 0, k1);
        PHASE_MM(0, 0, bfA);
        // p1
        LDB(0, 1, bfB);
        STAGE_A(1, 1, k1);
        PHASE_MM(0, 1, bfB);
        // p2
        LDA(0, 1);
        STAGE_B(0, k2);
        PHASE_MM(1, 1, bfB);
        // p3
        VMCNT2;
        PHASE_MM(1, 0, bfA);
        // p4
        LDA(1, 0); LDB(1, 0, bfA);
        STAGE_A(0, 0, k2);
        PHASE_MM(0, 0, bfA);
        // p5
        LDB(1, 1, bfB);
        STAGE_A(0, 1, k2);
        PHASE_MM(0, 1, bfB);
        // p6
        LDA(1, 1);
        STAGE_B(1, k3);
        PHASE_MM(1, 1, bfB);
        // p7
        VMCNT2;
        PHASE_MM(1, 0, bfA);
    }

    asm volatile("s_waitcnt vmcnt(0)" ::: "memory");

    if (MODE == 2) {
        bf16* qkv = (bf16*)outp;
#pragma unroll
        for (int mt = 0; mt < 4; mt++)
#pragma unroll
            for (int nt = 0; nt < 4; nt++) {
                f32x4 v = acc[mt][nt];
                const int gr0 = m0 + wr * 64 + mt * 16 + quad * 4;
                const int gc = n0 + wc * 64 + nt * 16 + lm;
                const int which = gc >> 10;  // 0=q 1=k 2=v
                const int h = (gc >> 6) & 15;
                const int d = gc & 63;
                const int b = gr0 >> 11, n = gr0 & 2047;
                if (which == 2) {
                    short4 pk;
                    pk.x = f2b(v[0]); pk.y = f2b(v[1]); pk.z = f2b(v[2]); pk.w = f2b(v[3]);
                    *(short4*)&qkv[2ull * 8388608 +
                                   ((size_t)((b * 16 + h) * 64 + d)) * 2048 + n] = pk;
                } else {
#pragma unroll
                    for (int r = 0; r < 4; r++) {
                        float val = v[r];
                        if (which == 0) val *= QSCALE;  // fold D^-0.5 * log2(e) into Q
                        qkv[(size_t)which * 8388608 +
                            ((size_t)((b * 16 + h) * 2048 + n + r)) * 64 + d] =
                            __float2bfloat16(val);
                    }
                }
            }
    } else {
        float* o = (float*)outp;
#pragma unroll
        for (int mt = 0; mt < 4; mt++)
#pragma unroll
            for (int nt = 0; nt < 4; nt++) {
                f32x4 v = acc[mt][nt];
                const int gr0 = m0 + wr * 64 + mt * 16 + quad * 4;
                const int gc = n0 + wc * 64 + nt * 16 + lm;
#pragma unroll
                for (int r = 0; r < 4; r++) o[(size_t)(gr0 + r) * 1024 + gc] = v[r];
            }
    }
#undef STAGE_A
#undef STAGE_B
#undef LDA
#undef LDB
#undef PHASE_MM
#undef VMCNT2
}

// ---------- MFMA flash attention v9 (verified PASS @ ~88 us): ONE barrier/tile ----------
// !!! The s_setprio pairs in this loop are LOAD-BEARING (R11 lesson): removing
// them broke numerics (absmax 7.7e-2). hipcc sinks/hoists register-only MFMA and
// lgkmcnt drains across inline-asm fences (guide rule #18); the setprio anchors
// pin the schedule so no wave crosses the tile-top barrier with outstanding
// ds_reads of the buffer the next DMA overwrites. Do not remove.
__global__ __launch_bounds__(256, 2) void attn_mfma_kernel(
    const unsigned short* __restrict__ Qg, const unsigned short* __restrict__ Kg,
    const unsigned short* __restrict__ Vtg, unsigned short* __restrict__ O) {
    __shared__ unsigned short Ks[2][64][64];   // [buf][key][d], XOR-8 swizzled
    __shared__ unsigned short Vs[2][64][64];   // [buf][d][key], XOR-8 swizzled
    __shared__ unsigned short Ps[4][4][16][64];// [wave][mt][q][key], XOR-8 swizzled
    const int tid = threadIdx.x;
    const int lane = tid & 63;
    const int w = tid >> 6;
    const int lm = lane & 15;
    const int quad = lane >> 4;
    const int bh = blockIdx.x & 63;        // same bh -> same XCD (id mod 8 fixed)
    const int n0 = (blockIdx.x >> 6) * 256;
    const size_t base = (size_t)bh * (2048 * 64);

    // Q as B-operand (pre-scaled QSCALE), resident all tiles; 64 q-rows per wave
    bf16x8 qf[4][2];
#pragma unroll
    for (int mt = 0; mt < 4; mt++)
#pragma unroll
        for (int ks = 0; ks < 2; ks++)
            qf[mt][ks] = *(const bf16x8*)&Qg[base +
                                            (size_t)(n0 + w * 64 + mt * 16 + lm) * 64 +
                                            ks * 32 + quad * 8];

    f32x4 accO[4][4] = {};
    float lst[4] = {0.f, 0.f, 0.f, 0.f};

    const int sr = lane >> 3;
    const int sg = (lane & 7) ^ sr;

    // prologue: stage K(0), V(0) into buf 0
#pragma unroll
    for (int j = 0; j < 2; j++) {
        const int row = w * 16 + j * 8 + sr;
        gload_lds16(&Vtg[base + (size_t)row * 2048 + sg * 8], &Vs[0][w * 16 + j * 8][0]);
        gload_lds16(&Kg[base + (size_t)row * 64 + sg * 8], &Ks[0][w * 16 + j * 8][0]);
    }

    int kb = 0;
    for (int t = 0; t < 32; t++) {
        // own DMA(t) landed (issued a full tile ago except t=0), then barrier:
        // all waves' DMA(t) visible AND all t-1 buf^1 reads complete.
        asm volatile("s_waitcnt vmcnt(0)" ::: "memory");
        __builtin_amdgcn_s_barrier();

        if (t + 1 < 32) {
            const int k0n = (t + 1) * 64;
#pragma unroll
            for (int j = 0; j < 2; j++) {
                const int row = w * 16 + j * 8 + sr;
                gload_lds16(&Vtg[base + (size_t)row * 2048 + k0n + sg * 8],
                            &Vs[kb ^ 1][w * 16 + j * 8][0]);
                gload_lds16(&Kg[base + (size_t)(k0n + row) * 64 + sg * 8],
                            &Ks[kb ^ 1][w * 16 + j * 8][0]);
            }
        }

        // ---- compute on buf kb ----
        bf16x8 kbf[4][2];
#pragma unroll
        for (int kt = 0; kt < 4; kt++)
#pragma unroll
            for (int ks = 0; ks < 2; ks++)
                kbf[kt][ks] = *(const bf16x8*)&Ks[kb][kt * 16 + lm]
                                                 [(((ks * 4 + quad) ^ (lm & 7)) * 8)];

        // per-mt: S^T = K·Q^T (8 MFMA) then exp2 + P^T store (s transient)
#pragma unroll
        for (int mt = 0; mt < 4; mt++) {
            f32x4 s[4];
            __builtin_amdgcn_s_setprio(1);
#pragma unroll
            for (int kt = 0; kt < 4; kt++) {
                f32x4 z = {};
                z = MFMA16(kbf[kt][0], qf[mt][0], z);
                s[kt] = MFMA16(kbf[kt][1], qf[mt][1], z);
            }
            __builtin_amdgcn_s_setprio(0);
            float ps = 0.f;
#pragma unroll
            for (int kt = 0; kt < 4; kt++) {
                const float p0 = exp2_fast(s[kt][0]);
                const float p1 = exp2_fast(s[kt][1]);
                const float p2 = exp2_fast(s[kt][2]);
                const float p3 = exp2_fast(s[kt][3]);
                ps += (p0 + p1) + (p2 + p3);
                short4 pk;
                pk.x = f2b(p0); pk.y = f2b(p1); pk.z = f2b(p2); pk.w = f2b(p3);
                const int g = kt * 2 + (quad >> 1);
                *(short4*)&Ps[w][mt][lm][((g ^ (lm & 7)) * 8) + (quad & 1) * 4] = pk;
            }
            lst[mt] += ps;
        }

        // PV: O^T += V^T·P^T (Vs[kb] visible since tile-top barrier; Ps wave-private)
        bf16x8 vbf[4][2];
#pragma unroll
        for (int nt = 0; nt < 4; nt++)
#pragma unroll
            for (int ks = 0; ks < 2; ks++)
                vbf[nt][ks] = *(const bf16x8*)&Vs[kb][nt * 16 + lm]
                                                 [(((ks * 4 + quad) ^ (lm & 7)) * 8)];
#pragma unroll
        for (int mt = 0; mt < 4; mt++) {
            bf16x8 pb0 = *(const bf16x8*)&Ps[w][mt][lm][(((quad) ^ (lm & 7)) * 8)];
            bf16x8 pb1 = *(const bf16x8*)&Ps[w][mt][lm][(((4 + quad) ^ (lm & 7)) * 8)];
            __builtin_amdgcn_s_setprio(1);
#pragma unroll
            for (int nt = 0; nt < 4; nt++) {
                f32x4 a = MFMA16(vbf[nt][0], pb0, accO[mt][nt]);
                accO[mt][nt] = MFMA16(vbf[nt][1], pb1, a);
            }
            __builtin_amdgcn_s_setprio(0);
        }

        kb ^= 1;
    }

#pragma unroll
    for (int mt = 0; mt < 4; mt++) {
        lst[mt] += __shfl_xor(lst[mt], 16);
        lst[mt] += __shfl_xor(lst[mt], 32);
    }

    const int b = bh >> 4, h = bh & 15;
#pragma unroll
    for (int mt = 0; mt < 4; mt++) {
        const float inv = 1.0f / lst[mt];
        const int n = n0 + w * 64 + mt * 16 + lm;
#pragma unroll
        for (int nt = 0; nt < 4; nt++) {
            short4 pk;
            pk.x = f2b(accO[mt][nt][0] * inv);
            pk.y = f2b(accO[mt][nt][1] * inv);
            pk.z = f2b(accO[mt][nt][2] * inv);
            pk.w = f2b(accO[mt][nt][3] * inv);
            *(short4*)&O[((size_t)(b * 2048 + n)) * 1024 + h * 64 + nt * 16 + quad * 4] = pk;
        }
    }
}

extern "C" void kernel_launch(void* const* d_in, const int* in_sizes, int n_in,
                              void* d_out, int out_size, void* d_ws, size_t ws_size,
                              hipStream_t stream) {
    const float* x = (const float*)d_in[0];      // [4,2048,1024] fp32
    const float* w_qkv = (const float*)d_in[1];  // [3072,1024] fp32
    const float* w_out = (const float*)d_in[2];  // [1024,1024] fp32
    float* out = (float*)d_out;                  // [4,2048,1024] fp32

    unsigned short* qkvb = (unsigned short*)d_ws;
    unsigned short* xb = qkvb + 3ull * 8388608;
    unsigned short* wqkvb = xb + 8388608;
    unsigned short* woutb = wqkvb + 3145728;

    // 0) fp32 -> bf16, single launch
    cvt3_kernel<<<6144, 256, 0, stream>>>(x, w_qkv, w_out, xb, wqkvb, woutb);
    // 1) QKV projection: 256x128 8-phase, 768 blocks = 3 exact rounds
    gemm256x128_kernel<2, 24><<<768, 512, 0, stream>>>(xb, wqkvb, (void*)qkvb);
    // 2) MFMA flash attention v9 (1 barrier/tile) -> bf16 attn_out
    attn_mfma_kernel<<<512, 256, 0, stream>>>(qkvb, qkvb + 8388608,
                                              qkvb + 2 * 8388608, xb);
    // 3) output projection: same 8-phase kernel, 256 blocks = 1 block/CU, 1 round
    gemm256x128_kernel<1, 8><<<256, 512, 0, stream>>>(xb, woutb, (void*)out);
}

// Round 14
// 242.728 us; speedup vs baseline: 1.0735x; 1.0357x over previous
//
#include <hip/hip_runtime.h>
#include <hip/hip_bf16.h>

typedef short bf16x8 __attribute__((ext_vector_type(8)));
typedef float f32x4 __attribute__((ext_vector_type(4)));
using bf16 = __hip_bfloat16;

#define MFMA16(a, b, c) __builtin_amdgcn_mfma_f32_16x16x32_bf16(a, b, c, 0, 0, 0)

typedef unsigned int u32;
typedef u32 __attribute__((address_space(1))) global_u32;
typedef u32 __attribute__((address_space(3))) lds_u32;

__device__ __forceinline__ void gload_lds16(const unsigned short* g, unsigned short* l) {
    // async 16B/lane global->LDS DMA; LDS dest = wave-uniform base + lane*16
    __builtin_amdgcn_global_load_lds((const global_u32*)g, (lds_u32*)l, 16, 0, 0);
}

__device__ __forceinline__ short f2b(float f) {
    __hip_bfloat16 h = __float2bfloat16(f);  // RNE
    return *reinterpret_cast<short*>(&h);
}

__device__ __forceinline__ float exp2_fast(float x) {
    float r;
    asm("v_exp_f32 %0, %1" : "=v"(r) : "v"(x));
    return r;
}

// Q pre-scale: D^-0.5 * log2(e); attn then uses exp2 -> saves one v_mul per score
#define QSCALE 0.18033688011112042f

// ---------- fp32 -> bf16 convert, all three inputs in ONE launch ----------
__global__ __launch_bounds__(256) void cvt3_kernel(const float* __restrict__ x,
                                                   const float* __restrict__ wq,
                                                   const float* __restrict__ wo,
                                                   unsigned short* __restrict__ xb,
                                                   unsigned short* __restrict__ wqb,
                                                   unsigned short* __restrict__ wob) {
    const int id = blockIdx.x;
    const float* src;
    unsigned short* dst;
    size_t off;
    if (id < 4096) {
        src = x; dst = xb; off = (size_t)id * 2048;
    } else if (id < 5632) {
        src = wq; dst = wqb; off = (size_t)(id - 4096) * 2048;
    } else {
        src = wo; dst = wob; off = (size_t)(id - 5632) * 2048;
    }
    const size_t i = off + (size_t)threadIdx.x * 8;
    float4 v0 = *(const float4*)(src + i);
    float4 v1 = *(const float4*)(src + i + 4);
    bf16x8 o;
    o[0] = f2b(v0.x); o[1] = f2b(v0.y); o[2] = f2b(v0.z); o[3] = f2b(v0.w);
    o[4] = f2b(v1.x); o[5] = f2b(v1.y); o[6] = f2b(v1.z); o[7] = f2b(v1.w);
    *(bf16x8*)(dst + i) = o;
}

// ---------- 256x128 4-phase bf16 GEMM (R13's verified K-loop, phases merged 2:1) ----------
// R14 change: at K=1024 the 8-phase pays 2 barriers per 8 MFMA (16 barriers/iter,
// 128 sync points/block) — barrier-overhead-dominated in the short-K regime.
// 4-phase doubles MFMA per barrier-pair to 16 (full A-column x one B-half):
//  p0: LDA full + LDB both (buf0) | stage A(t+1)->b1 (4) | MM(nh0) 16 MFMA
//  p1:                             | stage B(t+2)->b0 (2) | vmcnt(2) | MM(nh1)
//  p2/p3: mirror on buf1, staging A(t+2)->b0, B(t+3)->b1.
// WAR: every STAGE targets a region drained at a prior phase's lgkmcnt(0)+barrier.
// RAW: vmcnt(2) at p1/p3 leaves only the newest B-stage in flight (same counted
// value as the verified 8-phase; chronological audit in session notes R14).
// Per-accumulator MFMA order is UNCHANGED -> bit-identical results.
// MODE 2: QKV scatter. MODE 1: fp32 row-major. NTN = N/128.
template <int MODE, int NTN>
__global__ __launch_bounds__(512, 2) void gemm256x128_kernel(
    const unsigned short* __restrict__ A,   // [M,1024] bf16
    const unsigned short* __restrict__ W,   // [N,1024] bf16
    void* __restrict__ outp) {
    __shared__ unsigned short As[2][256][64];
    __shared__ unsigned short Bs[2][128][64];
    const int tid = threadIdx.x;
    const int lane = tid & 63;
    const int w = tid >> 6;               // 0..7
    const int wr = w >> 1, wc = w & 1;    // 4M x 2N wave grid
    const int lm = lane & 15, quad = lane >> 4;

    constexpr int TPX = 4 * NTN;          // tiles per XCD = (32*NTN)/8
    const int id = blockIdx.x;
    const int xs = (id & 7) * TPX + (id >> 3);
    const int n0 = (xs % NTN) * 128;
    const int m0 = (xs / NTN) * 256;

    const int sr = lane >> 3;
    const int sg = (lane & 7) ^ sr;
    const unsigned short* Ab = A + (size_t)(m0 + w * 8 + sr) * 1024 + sg * 8;
    const unsigned short* Wb = W + (size_t)(n0 + w * 8 + sr) * 1024 + sg * 8;

    f32x4 acc[4][4] = {};
    bf16x8 af[4][2];   // FULL A column: 4 m-frags x 2 k-steps (32 VGPR)
    bf16x8 bfA[2][2];  // nh=0 B frags
    bf16x8 bfB[2][2];  // nh=1 B frags

#define STAGE_A(buf, half, kk)                                                     \
    do {                                                                           \
        gload_lds16(Ab + (size_t)((half) * 128) * 1024 + (kk),                     \
                    &As[buf][(half) * 128 + w * 8][0]);                            \
        gload_lds16(Ab + (size_t)((half) * 128 + 64) * 1024 + (kk),                \
                    &As[buf][(half) * 128 + 64 + w * 8][0]);                       \
    } while (0)
#define STAGE_B(buf, kk)                                                           \
    do {                                                                           \
        gload_lds16(Wb + (kk), &Bs[buf][w * 8][0]);                                \
        gload_lds16(Wb + (size_t)64 * 1024 + (kk), &Bs[buf][64 + w * 8][0]);       \
    } while (0)
#define LDA_FULL(buf)                                                              \
    do {                                                                           \
        _Pragma("unroll") for (int mt2 = 0; mt2 < 4; mt2++)                        \
            _Pragma("unroll") for (int ks = 0; ks < 2; ks++)                       \
                af[mt2][ks] =                                                      \
                    *(const bf16x8*)&As[buf][wr * 64 + mt2 * 16 + lm]              \
                                        [(((quad + ks * 4) ^ (lm & 7)) * 8)];      \
    } while (0)
#define LDB(buf, nh, DST)                                                          \
    do {                                                                           \
        _Pragma("unroll") for (int nt2 = 0; nt2 < 2; nt2++)                        \
            _Pragma("unroll") for (int ks = 0; ks < 2; ks++)                       \
                DST[nt2][ks] =                                                     \
                    *(const bf16x8*)&Bs[buf][wc * 64 + ((nh) * 2 + nt2) * 16 + lm] \
                                        [(((quad + ks * 4) ^ (lm & 7)) * 8)];      \
    } while (0)
// one barrier-pair around 16 MFMA: full A-column x one B-half
#define PHASE_MM2(nh, BF)                                                          \
    do {                                                                           \
        __builtin_amdgcn_s_barrier();                                              \
        asm volatile("s_waitcnt lgkmcnt(0)" ::: "memory");                         \
        __builtin_amdgcn_s_setprio(1);                                             \
        _Pragma("unroll") for (int mt2 = 0; mt2 < 4; mt2++)                        \
            _Pragma("unroll") for (int nt2 = 0; nt2 < 2; nt2++) {                  \
                f32x4 t0 = MFMA16(af[mt2][0], BF[nt2][0],                          \
                                  acc[mt2][(nh) * 2 + nt2]);                       \
                acc[mt2][(nh) * 2 + nt2] =                                         \
                    MFMA16(af[mt2][1], BF[nt2][1], t0);                            \
            }                                                                      \
        __builtin_amdgcn_s_setprio(0);                                             \
        __builtin_amdgcn_s_barrier();                                              \
    } while (0)
#define VMCNT2 asm volatile("s_waitcnt vmcnt(2)" ::: "memory")

    // prologue: tile0 fully (6 issues), tile1's B (2, stays in flight)
    STAGE_A(0, 0, 0); STAGE_A(0, 1, 0);
    STAGE_B(0, 0);
    STAGE_B(1, 64);
    VMCNT2;  // tile0's 6 landed; B(t1) may fly
    __builtin_amdgcn_s_barrier();

    for (int i = 0; i < 8; i++) {
        const int t = 2 * i;
        const int k1 = (t + 1) * 64;
        const int k2 = (t + 2 < 16) ? (t + 2) * 64 : 0;  // tail: harmless garbage
        const int k3 = (t + 3 < 16) ? (t + 3) * 64 : 0;  // staged, never consumed
        // p0: buf0 reads + A(t+1) stage + MM(nh0)
        LDA_FULL(0);
        LDB(0, 0, bfA); LDB(0, 1, bfB);
        STAGE_A(1, 0, k1); STAGE_A(1, 1, k1);
        PHASE_MM2(0, bfA);
        // p1: B(t+2) stage (Bs[0] drained at p0) + counted wait + MM(nh1)
        STAGE_B(0, k2);
        VMCNT2;  // A(t+1),B(t+1) landed; only B(t+2) in flight
        PHASE_MM2(1, bfB);
        // p2: buf1 reads + A(t+2) stage + MM(nh0)
        LDA_FULL(1);
        LDB(1, 0, bfA); LDB(1, 1, bfB);
        STAGE_A(0, 0, k2); STAGE_A(0, 1, k2);
        PHASE_MM2(0, bfA);
        // p3: B(t+3) stage + counted wait + MM(nh1)
        STAGE_B(1, k3);
        VMCNT2;  // A(t+2),B(t+2) landed; only B(t+3) in flight
        PHASE_MM2(1, bfB);
    }

    // drain trailing (garbage) DMA loads before wave exit
    asm volatile("s_waitcnt vmcnt(0)" ::: "memory");

    if (MODE == 2) {
        bf16* qkv = (bf16*)outp;
#pragma unroll
        for (int mt = 0; mt < 4; mt++)
#pragma unroll
            for (int nt = 0; nt < 4; nt++) {
                f32x4 v = acc[mt][nt];
                const int gr0 = m0 + wr * 64 + mt * 16 + quad * 4;
                const int gc = n0 + wc * 64 + nt * 16 + lm;
                const int which = gc >> 10;  // 0=q 1=k 2=v
                const int h = (gc >> 6) & 15;
                const int d = gc & 63;
                const int b = gr0 >> 11, n = gr0 & 2047;
                if (which == 2) {
                    short4 pk;
                    pk.x = f2b(v[0]); pk.y = f2b(v[1]); pk.z = f2b(v[2]); pk.w = f2b(v[3]);
                    *(short4*)&qkv[2ull * 8388608 +
                                   ((size_t)((b * 16 + h) * 64 + d)) * 2048 + n] = pk;
                } else {
#pragma unroll
                    for (int r = 0; r < 4; r++) {
                        float val = v[r];
                        if (which == 0) val *= QSCALE;  // fold D^-0.5 * log2(e) into Q
                        qkv[(size_t)which * 8388608 +
                            ((size_t)((b * 16 + h) * 2048 + n + r)) * 64 + d] =
                            __float2bfloat16(val);
                    }
                }
            }
    } else {
        float* o = (float*)outp;
#pragma unroll
        for (int mt = 0; mt < 4; mt++)
#pragma unroll
            for (int nt = 0; nt < 4; nt++) {
                f32x4 v = acc[mt][nt];
                const int gr0 = m0 + wr * 64 + mt * 16 + quad * 4;
                const int gc = n0 + wc * 64 + nt * 16 + lm;
#pragma unroll
                for (int r = 0; r < 4; r++) o[(size_t)(gr0 + r) * 1024 + gc] = v[r];
            }
    }
#undef STAGE_A
#undef STAGE_B
#undef LDA_FULL
#undef LDB
#undef PHASE_MM2
#undef VMCNT2
}

// ---------- MFMA flash attention v9 (verified PASS @ ~87 us): ONE barrier/tile ----------
// !!! The s_setprio pairs in this loop are LOAD-BEARING (R11 lesson): removing
// them broke numerics (absmax 7.7e-2). hipcc sinks/hoists register-only MFMA and
// lgkmcnt drains across inline-asm fences (guide rule #18); the setprio anchors
// pin the schedule so no wave crosses the tile-top barrier with outstanding
// ds_reads of the buffer the next DMA overwrites. Do not remove.
__global__ __launch_bounds__(256, 2) void attn_mfma_kernel(
    const unsigned short* __restrict__ Qg, const unsigned short* __restrict__ Kg,
    const unsigned short* __restrict__ Vtg, unsigned short* __restrict__ O) {
    __shared__ unsigned short Ks[2][64][64];   // [buf][key][d], XOR-8 swizzled
    __shared__ unsigned short Vs[2][64][64];   // [buf][d][key], XOR-8 swizzled
    __shared__ unsigned short Ps[4][4][16][64];// [wave][mt][q][key], XOR-8 swizzled
    const int tid = threadIdx.x;
    const int lane = tid & 63;
    const int w = tid >> 6;
    const int lm = lane & 15;
    const int quad = lane >> 4;
    const int bh = blockIdx.x & 63;        // same bh -> same XCD (id mod 8 fixed)
    const int n0 = (blockIdx.x >> 6) * 256;
    const size_t base = (size_t)bh * (2048 * 64);

    // Q as B-operand (pre-scaled QSCALE), resident all tiles; 64 q-rows per wave
    bf16x8 qf[4][2];
#pragma unroll
    for (int mt = 0; mt < 4; mt++)
#pragma unroll
        for (int ks = 0; ks < 2; ks++)
            qf[mt][ks] = *(const bf16x8*)&Qg[base +
                                            (size_t)(n0 + w * 64 + mt * 16 + lm) * 64 +
                                            ks * 32 + quad * 8];

    f32x4 accO[4][4] = {};
    float lst[4] = {0.f, 0.f, 0.f, 0.f};

    const int sr = lane >> 3;
    const int sg = (lane & 7) ^ sr;

    // prologue: stage K(0), V(0) into buf 0
#pragma unroll
    for (int j = 0; j < 2; j++) {
        const int row = w * 16 + j * 8 + sr;
        gload_lds16(&Vtg[base + (size_t)row * 2048 + sg * 8], &Vs[0][w * 16 + j * 8][0]);
        gload_lds16(&Kg[base + (size_t)row * 64 + sg * 8], &Ks[0][w * 16 + j * 8][0]);
    }

    int kb = 0;
    for (int t = 0; t < 32; t++) {
        // own DMA(t) landed (issued a full tile ago except t=0), then barrier:
        // all waves' DMA(t) visible AND all t-1 buf^1 reads complete.
        asm volatile("s_waitcnt vmcnt(0)" ::: "memory");
        __builtin_amdgcn_s_barrier();

        if (t + 1 < 32) {
            const int k0n = (t + 1) * 64;
#pragma unroll
            for (int j = 0; j < 2; j++) {
                const int row = w * 16 + j * 8 + sr;
                gload_lds16(&Vtg[base + (size_t)row * 2048 + k0n + sg * 8],
                            &Vs[kb ^ 1][w * 16 + j * 8][0]);
                gload_lds16(&Kg[base + (size_t)(k0n + row) * 64 + sg * 8],
                            &Ks[kb ^ 1][w * 16 + j * 8][0]);
            }
        }

        // ---- compute on buf kb ----
        bf16x8 kbf[4][2];
#pragma unroll
        for (int kt = 0; kt < 4; kt++)
#pragma unroll
            for (int ks = 0; ks < 2; ks++)
                kbf[kt][ks] = *(const bf16x8*)&Ks[kb][kt * 16 + lm]
                                                 [(((ks * 4 + quad) ^ (lm & 7)) * 8)];

        // per-mt: S^T = K·Q^T (8 MFMA) then exp2 + P^T store (s transient)
#pragma unroll
        for (int mt = 0; mt < 4; mt++) {
            f32x4 s[4];
            __builtin_amdgcn_s_setprio(1);
#pragma unroll
            for (int kt = 0; kt < 4; kt++) {
                f32x4 z = {};
                z = MFMA16(kbf[kt][0], qf[mt][0], z);
                s[kt] = MFMA16(kbf[kt][1], qf[mt][1], z);
            }
            __builtin_amdgcn_s_setprio(0);
            float ps = 0.f;
#pragma unroll
            for (int kt = 0; kt < 4; kt++) {
                const float p0 = exp2_fast(s[kt][0]);
                const float p1 = exp2_fast(s[kt][1]);
                const float p2 = exp2_fast(s[kt][2]);
                const float p3 = exp2_fast(s[kt][3]);
                ps += (p0 + p1) + (p2 + p3);
                short4 pk;
                pk.x = f2b(p0); pk.y = f2b(p1); pk.z = f2b(p2); pk.w = f2b(p3);
                const int g = kt * 2 + (quad >> 1);
                *(short4*)&Ps[w][mt][lm][((g ^ (lm & 7)) * 8) + (quad & 1) * 4] = pk;
            }
            lst[mt] += ps;
        }

        // PV: O^T += V^T·P^T (Vs[kb] visible since tile-top barrier; Ps wave-private)
        bf16x8 vbf[4][2];
#pragma unroll
        for (int nt = 0; nt < 4; nt++)
#pragma unroll
            for (int ks = 0; ks < 2; ks++)
                vbf[nt][ks] = *(const bf16x8*)&Vs[kb][nt * 16 + lm]
                                                 [(((ks * 4 + quad) ^ (lm & 7)) * 8)];
#pragma unroll
        for (int mt = 0; mt < 4; mt++) {
            bf16x8 pb0 = *(const bf16x8*)&Ps[w][mt][lm][(((quad) ^ (lm & 7)) * 8)];
            bf16x8 pb1 = *(const bf16x8*)&Ps[w][mt][lm][(((4 + quad) ^ (lm & 7)) * 8)];
            __builtin_amdgcn_s_setprio(1);
#pragma unroll
            for (int nt = 0; nt < 4; nt++) {
                f32x4 a = MFMA16(vbf[nt][0], pb0, accO[mt][nt]);
                accO[mt][nt] = MFMA16(vbf[nt][1], pb1, a);
            }
            __builtin_amdgcn_s_setprio(0);
        }

        kb ^= 1;
    }

#pragma unroll
    for (int mt = 0; mt < 4; mt++) {
        lst[mt] += __shfl_xor(lst[mt], 16);
        lst[mt] += __shfl_xor(lst[mt], 32);
    }

    const int b = bh >> 4, h = bh & 15;
#pragma unroll
    for (int mt = 0; mt < 4; mt++) {
        const float inv = 1.0f / lst[mt];
        const int n = n0 + w * 64 + mt * 16 + lm;
#pragma unroll
        for (int nt = 0; nt < 4; nt++) {
            short4 pk;
            pk.x = f2b(accO[mt][nt][0] * inv);
            pk.y = f2b(accO[mt][nt][1] * inv);
            pk.z = f2b(accO[mt][nt][2] * inv);
            pk.w = f2b(accO[mt][nt][3] * inv);
            *(short4*)&O[((size_t)(b * 2048 + n)) * 1024 + h * 64 + nt * 16 + quad * 4] = pk;
        }
    }
}

extern "C" void kernel_launch(void* const* d_in, const int* in_sizes, int n_in,
                              void* d_out, int out_size, void* d_ws, size_t ws_size,
                              hipStream_t stream) {
    const float* x = (const float*)d_in[0];      // [4,2048,1024] fp32
    const float* w_qkv = (const float*)d_in[1];  // [3072,1024] fp32
    const float* w_out = (const float*)d_in[2];  // [1024,1024] fp32
    float* out = (float*)d_out;                  // [4,2048,1024] fp32

    unsigned short* qkvb = (unsigned short*)d_ws;
    unsigned short* xb = qkvb + 3ull * 8388608;
    unsigned short* wqkvb = xb + 8388608;
    unsigned short* woutb = wqkvb + 3145728;

    // 0) fp32 -> bf16, single launch
    cvt3_kernel<<<6144, 256, 0, stream>>>(x, w_qkv, w_out, xb, wqkvb, woutb);
    // 1) QKV projection: 256x128 4-phase, 768 blocks = 3 exact rounds
    gemm256x128_kernel<2, 24><<<768, 512, 0, stream>>>(xb, wqkvb, (void*)qkvb);
    // 2) MFMA flash attention v9 (1 barrier/tile) -> bf16 attn_out
    attn_mfma_kernel<<<512, 256, 0, stream>>>(qkvb, qkvb + 8388608,
                                              qkvb + 2 * 8388608, xb);
    // 3) output projection: same 4-phase kernel, 256 blocks = 1 block/CU, 1 round
    gemm256x128_kernel<1, 8><<<256, 512, 0, stream>>>(xb, woutb, (void*)out);
}